// Round 4
// baseline (188.971 us; speedup 1.0000x reference)
//
#include <hip/hip_runtime.h>

#define T_SEQ 50
#define BATCH 8192
#define INPUT 33
#define HID   256
#define BTILE 16
#define NTH   512

typedef __attribute__((ext_vector_type(8))) short short8;
typedef __attribute__((ext_vector_type(4))) float float4v;

// LDS layout (units: shorts). Double-buffered h and x. 21.5 KB/block ->
// 2 blocks/CU (the round-4 lever: overlap one block's store-drain with the
// other block's compute). Row pad +8 shorts -> free 2-way bank aliasing.
#define H_STRIDE 264                       // 256 + 8
#define X_STRIDE 72                        // 64 + 8
#define H0 0
#define H1 (BTILE * H_STRIDE)              // 4224
#define X0 (2 * BTILE * H_STRIDE)          // 8448
#define X1 (X0 + BTILE * X_STRIDE)         // 9600
#define LDS_SHORTS (X1 + BTILE * X_STRIDE) // 10752 shorts = 21504 B

__device__ __forceinline__ short f2bf(float v) {   // RNE f32 -> bf16 bits
  unsigned u = __builtin_bit_cast(unsigned, v);
  u = (u + 0x7FFFu + ((u >> 16) & 1u)) >> 16;
  return (short)u;
}

// One recurrence step (BTILE=16: single 16-row A block, 20 MFMA/wave).
// Single barrier per step; no vmcnt drain at the barrier (stores retire
// across steps, bounded only by the in-order x-load wait).
#define CSTEP(HR, XR, HW, XW, T)                                              \
  {                                                                           \
    float xp0 = 0.f, xp1 = 0.f;                                               \
    const bool more = (T) + 1 < T_SEQ;                                        \
    if (more) {                                                               \
      const float* xt1 = xpf + (size_t)((T) + 1) * xstep;                     \
      xp0 = xt1[e0];                                                          \
      if (p1) xp1 = xt1[e1];                                                  \
    }                                                                         \
    float4v acc[2];                                                           \
    _Pragma("unroll") for (int n = 0; n < 2; ++n)                             \
      _Pragma("unroll") for (int i = 0; i < 4; ++i)                           \
        acc[n][i] = hst[n][i] + bc[n];                                        \
    const short* hb = lds + (HR);                                             \
    const short* xb = lds + (XR);                                             \
    _Pragma("unroll") for (int ks = 0; ks < 8; ++ks) {                        \
      const int k = ks * 32 + kq * 8;                                         \
      short8 a0 = *(const short8*)(hb + colA * H_STRIDE + k);                 \
      acc[0] = __builtin_amdgcn_mfma_f32_16x16x32_bf16(a0, wf[0][ks], acc[0], 0, 0, 0); \
      acc[1] = __builtin_amdgcn_mfma_f32_16x16x32_bf16(a0, wf[1][ks], acc[1], 0, 0, 0); \
    }                                                                         \
    _Pragma("unroll") for (int kb = 0; kb < 2; ++kb) {                        \
      const int k = kb * 32 + kq * 8;                                         \
      short8 a0 = *(const short8*)(xb + colA * X_STRIDE + k);                 \
      acc[0] = __builtin_amdgcn_mfma_f32_16x16x32_bf16(a0, win[0][kb], acc[0], 0, 0, 0); \
      acc[1] = __builtin_amdgcn_mfma_f32_16x16x32_bf16(a0, win[1][kb], acc[1], 0, 0, 0); \
    }                                                                         \
    _Pragma("unroll") for (int n = 0; n < 2; ++n)                             \
      _Pragma("unroll") for (int i = 0; i < 4; ++i) {                         \
        float hn = fmaxf(0.5f * acc[n][i], 0.0f);                             \
        hst[n][i] = hn;                                                       \
        outp[i * HID + n * 16] = hn;                                          \
      }                                                                       \
    _Pragma("unroll") for (int n = 0; n < 2; ++n)                             \
      _Pragma("unroll") for (int i = 0; i < 4; ++i)                           \
        lds[(HW) + (kq * 4 + i) * H_STRIDE + c0 + n * 16 + colA] =            \
            f2bf(hst[n][i]);                                                  \
    if (more) {                                                               \
      lds[(XW) + r0 * X_STRIDE + c0x] = f2bf(xp0);                            \
      if (p1) lds[(XW) + r1 * X_STRIDE + c1x] = f2bf(xp1);                    \
    }                                                                         \
    __builtin_amdgcn_sched_barrier(0);                                        \
    asm volatile("s_waitcnt lgkmcnt(0)" ::: "memory");                        \
    __builtin_amdgcn_s_barrier();                                             \
    __builtin_amdgcn_sched_barrier(0);                                        \
    outp += outstep;                                                          \
  }

__global__ __launch_bounds__(NTH, 4)
void ctrnn_kernel(const float* __restrict__ x, const int* __restrict__ sub_id,
                  const float* __restrict__ gates, const float* __restrict__ W_in,
                  const float* __restrict__ b_in, const float* __restrict__ W_h,
                  const float* __restrict__ b_h, float* __restrict__ out)
{
  __shared__ short lds[LDS_SHORTS];
  const int tid  = threadIdx.x;
  const int lane = tid & 63;
  const int wave = tid >> 6;
  const int colA = lane & 15;   // MFMA row/col-within-tile index
  const int kq   = lane >> 4;   // k-quadrant / C-row group
  const int c0   = wave * 32;   // wave's output-column base (8 waves x 32)
  const int brow0 = blockIdx.x * BTILE;

  const int sid = sub_id[0];
  const float* grow = gates + sid * HID;

  // ---- zero all LDS (h0 = 0; x pad columns stay 0 forever) ----
  {
    int* ldsi = (int*)lds;
    #pragma unroll 4
    for (int i = tid; i < LDS_SHORTS / 2; i += NTH) ldsi[i] = 0;
  }

  // ---- t-invariant operands in REGISTERS ----
  short8 wf[2][8];   // B-fragments of W_h' = diag(g)*W_h  (64 VGPRs)
  short8 win[2][2];  // B-fragments of W_in (zero-padded K=64)
  float  bc[2];
  #pragma unroll
  for (int n = 0; n < 2; ++n) {
    const int col = c0 + n * 16 + colA;
    const float g = grow[col];
    #pragma unroll
    for (int ks = 0; ks < 8; ++ks) {
      const float* wp = W_h + col * HID + ks * 32 + kq * 8;
      float4v w0 = *(const float4v*)wp;
      float4v w1 = *(const float4v*)(wp + 4);
      short8 f;
      f[0] = f2bf(g * w0[0]); f[1] = f2bf(g * w0[1]);
      f[2] = f2bf(g * w0[2]); f[3] = f2bf(g * w0[3]);
      f[4] = f2bf(g * w1[0]); f[5] = f2bf(g * w1[1]);
      f[6] = f2bf(g * w1[2]); f[7] = f2bf(g * w1[3]);
      wf[n][ks] = f;
    }
    #pragma unroll
    for (int kb = 0; kb < 2; ++kb) {
      short8 f;
      #pragma unroll
      for (int j = 0; j < 8; ++j) {
        int kk = kb * 32 + kq * 8 + j;
        f[j] = (kk < INPUT) ? f2bf(W_in[col * INPUT + kk]) : (short)0;
      }
      win[n][kb] = f;
    }
    bc[n] = b_in[col] + g * b_h[col];
  }

  __syncthreads();   // zero-fill complete before x0 staging

  // ---- stage x_0 into buffer 0 ----
  {
    const float* xt = x + (size_t)brow0 * INPUT;
    for (int e = tid; e < BTILE * INPUT; e += NTH) {
      int r = e / INPUT, c = e - r * INPUT;
      lds[X0 + r * X_STRIDE + c] = f2bf(xt[e]);
    }
  }

  // x-prefetch invariants: BTILE*INPUT = 528 elems over 512 threads
  const int e0 = tid, e1 = tid + NTH;
  const int r0 = e0 / INPUT, c0x = e0 - r0 * INPUT;
  const int r1 = e1 / INPUT, c1x = e1 - r1 * INPUT;
  const bool p1 = (e1 < BTILE * INPUT);

  // persistent f32 h master at MFMA C-layout: col=c0+n*16+colA, row=kq*4+i
  float4v hst[2];
  #pragma unroll
  for (int n = 0; n < 2; ++n)
    #pragma unroll
    for (int i = 0; i < 4; ++i) hst[n][i] = 0.0f;

  float* outp = out + (size_t)(brow0 + kq * 4) * HID + c0 + colA;
  const int outstep = BATCH * HID;
  const float* xpf = x + (size_t)brow0 * INPUT;
  const int xstep = BATCH * INPUT;

  __syncthreads();   // x0 staged; h0 zeroed

  #pragma unroll 1
  for (int t2 = 0; t2 < T_SEQ / 2; ++t2) {
    CSTEP(H0, X0, H1, X1, 2 * t2);       // even step: read buf0, write buf1
    CSTEP(H1, X1, H0, X0, 2 * t2 + 1);   // odd step:  read buf1, write buf0
  }

  // h_last = h after step T-1
  {
    float* hp = out + (size_t)T_SEQ * BATCH * HID +
                (size_t)(brow0 + kq * 4) * HID + c0 + colA;
    #pragma unroll
    for (int n = 0; n < 2; ++n)
      #pragma unroll
      for (int i = 0; i < 4; ++i)
        hp[i * HID + n * 16] = hst[n][i];
  }
}

extern "C" void kernel_launch(void* const* d_in, const int* in_sizes, int n_in,
                              void* d_out, int out_size, void* d_ws, size_t ws_size,
                              hipStream_t stream) {
  const float* x    = (const float*)d_in[0];
  const int*   sid  = (const int*)  d_in[1];
  const float* gts  = (const float*)d_in[2];
  const float* W_in = (const float*)d_in[3];
  const float* b_in = (const float*)d_in[4];
  const float* W_h  = (const float*)d_in[5];
  const float* b_h  = (const float*)d_in[6];
  float* out = (float*)d_out;

  ctrnn_kernel<<<BATCH / BTILE, NTH, 0, stream>>>(x, sid, gts, W_in, b_in, W_h, b_h, out);
}

// Round 5
// 119.190 us; speedup vs baseline: 1.5855x; 1.5855x over previous
//
#include <hip/hip_runtime.h>

#define T_SEQ 50
#define BATCH 8192
#define INPUT 33
#define HID   256
#define BTILE 32
#define NTH   512

typedef __attribute__((ext_vector_type(8))) short short8;
typedef __attribute__((ext_vector_type(4))) float float4v;

// bf16 h / x staging, double-buffered (units: shorts)
#define H_STRIDE 264                       // 256 + 8 pad (2-way aliasing = free)
#define X_STRIDE 72                        // 64 + 8
#define H0 0
#define H1 (BTILE * H_STRIDE)              // 8448
#define X0 (2 * BTILE * H_STRIDE)          // 16896
#define X1 (X0 + BTILE * X_STRIDE)         // 19200
#define LDS_SHORTS (X1 + BTILE * X_STRIDE) // 21504 shorts = 43008 B

// f32 out-stage, double-buffered (units: floats). Stride 260:
//  - rows stay 16B-aligned (260*4 = 1040)
//  - C-layout writes: bank = (4*row+col)%32 -> kq groups land {0,16,0,16} = 2-way (free)
//  - b128 row read-back: each 16-lane group covers all 32 banks once = conflict-free
#define OUT_STRIDE 260
#define OUTBUF (BTILE * OUT_STRIDE)        // 8320 floats
// total LDS = 43008 + 2*8320*4 = 109568 B  (1 block/CU)

__device__ __forceinline__ short f2bf(float v) {   // RNE f32 -> bf16 bits
  unsigned u = __builtin_bit_cast(unsigned, v);
  u = (u + 0x7FFFu + ((u >> 16) & 1u)) >> 16;
  return (short)u;
}

// One step. Read h/x from HR/XR, write next h/x to HW/XW, stage f32 output in
// outs[OW]. ONE barrier per step (all LDS buffers double-buffered); stores are
// contiguous 1KB-per-instruction dwordx4 issued after the barrier and retire
// during the next step's compute (no vmcnt drain anywhere in the loop).
#define CSTEP(HR, XR, HW, XW, OW, T)                                          \
  {                                                                           \
    float xp0 = 0.f, xp1 = 0.f, xp2 = 0.f;                                    \
    const bool more = (T) + 1 < T_SEQ;                                        \
    if (more) {                                                               \
      const float* xt1 = xpf + (size_t)((T) + 1) * xstep;                     \
      xp0 = xt1[e0]; xp1 = xt1[e1];                                           \
      if (p2) xp2 = xt1[e2];                                                  \
    }                                                                         \
    float4v acc[2][2];                                                        \
    _Pragma("unroll") for (int m = 0; m < 2; ++m)                             \
      _Pragma("unroll") for (int n = 0; n < 2; ++n)                           \
        _Pragma("unroll") for (int i = 0; i < 4; ++i)                         \
          acc[m][n][i] = hst[m][n][i] + bc[n];                                \
    const short* hb = lds + (HR);                                             \
    const short* xb = lds + (XR);                                             \
    _Pragma("unroll") for (int ks = 0; ks < 8; ++ks) {                        \
      const int k = ks * 32 + kq * 8;                                         \
      short8 a0 = *(const short8*)(hb + colA * H_STRIDE + k);                 \
      short8 a1 = *(const short8*)(hb + (16 + colA) * H_STRIDE + k);          \
      acc[0][0] = __builtin_amdgcn_mfma_f32_16x16x32_bf16(a0, wf[0][ks], acc[0][0], 0, 0, 0); \
      acc[0][1] = __builtin_amdgcn_mfma_f32_16x16x32_bf16(a0, wf[1][ks], acc[0][1], 0, 0, 0); \
      acc[1][0] = __builtin_amdgcn_mfma_f32_16x16x32_bf16(a1, wf[0][ks], acc[1][0], 0, 0, 0); \
      acc[1][1] = __builtin_amdgcn_mfma_f32_16x16x32_bf16(a1, wf[1][ks], acc[1][1], 0, 0, 0); \
    }                                                                         \
    _Pragma("unroll") for (int kb = 0; kb < 2; ++kb) {                        \
      const int k = kb * 32 + kq * 8;                                         \
      short8 a0 = *(const short8*)(xb + colA * X_STRIDE + k);                 \
      short8 a1 = *(const short8*)(xb + (16 + colA) * X_STRIDE + k);          \
      acc[0][0] = __builtin_amdgcn_mfma_f32_16x16x32_bf16(a0, win[0][kb], acc[0][0], 0, 0, 0); \
      acc[0][1] = __builtin_amdgcn_mfma_f32_16x16x32_bf16(a0, win[1][kb], acc[0][1], 0, 0, 0); \
      acc[1][0] = __builtin_amdgcn_mfma_f32_16x16x32_bf16(a1, win[0][kb], acc[1][0], 0, 0, 0); \
      acc[1][1] = __builtin_amdgcn_mfma_f32_16x16x32_bf16(a1, win[1][kb], acc[1][1], 0, 0, 0); \
    }                                                                         \
    float* osw = outs + (OW) * OUTBUF;                                        \
    _Pragma("unroll") for (int m = 0; m < 2; ++m)                             \
      _Pragma("unroll") for (int n = 0; n < 2; ++n)                           \
        _Pragma("unroll") for (int i = 0; i < 4; ++i) {                       \
          float hn = fmaxf(0.5f * acc[m][n][i], 0.0f);                        \
          hst[m][n][i] = hn;                                                  \
          const int row = m * 16 + kq * 4 + i;                                \
          osw[row * OUT_STRIDE + c0 + n * 16 + colA] = hn;                    \
          lds[(HW) + row * H_STRIDE + c0 + n * 16 + colA] = f2bf(hn);         \
        }                                                                     \
    if (more) {                                                               \
      lds[(XW) + r0 * X_STRIDE + c0x] = f2bf(xp0);                            \
      lds[(XW) + r1 * X_STRIDE + c1x] = f2bf(xp1);                            \
      if (p2) lds[(XW) + r2 * X_STRIDE + c2x] = f2bf(xp2);                    \
    }                                                                         \
    __builtin_amdgcn_sched_barrier(0);                                        \
    asm volatile("s_waitcnt lgkmcnt(0)" ::: "memory");                        \
    __builtin_amdgcn_s_barrier();                                             \
    __builtin_amdgcn_sched_barrier(0);                                        \
    _Pragma("unroll") for (int j = 0; j < 4; ++j) {                           \
      float4v v = *(const float4v*)(osw + (4 * wave + j) * OUT_STRIDE + 4 * lane); \
      *(float4v*)(outg + j * HID) = v;                                        \
    }                                                                         \
    outg += outstep;                                                          \
  }

__global__ __launch_bounds__(NTH, 2)
void ctrnn_kernel(const float* __restrict__ x, const int* __restrict__ sub_id,
                  const float* __restrict__ gates, const float* __restrict__ W_in,
                  const float* __restrict__ b_in, const float* __restrict__ W_h,
                  const float* __restrict__ b_h, float* __restrict__ out)
{
  __shared__ short lds[LDS_SHORTS];
  __shared__ float outs[2 * OUTBUF];
  const int tid  = threadIdx.x;
  const int lane = tid & 63;
  const int wave = tid >> 6;
  const int colA = lane & 15;   // MFMA row/col-within-tile index
  const int kq   = lane >> 4;   // k-quadrant / C-row group
  const int c0   = wave * 32;   // wave's output-column base (8 waves x 32)
  const int brow0 = blockIdx.x * BTILE;

  const int sid = sub_id[0];
  const float* grow = gates + sid * HID;

  // ---- zero h/x staging (h0 = 0; x pad columns stay 0 forever) ----
  {
    int* ldsi = (int*)lds;
    #pragma unroll 4
    for (int i = tid; i < LDS_SHORTS / 2; i += NTH) ldsi[i] = 0;
  }

  // ---- t-invariant operands in REGISTERS ----
  short8 wf[2][8];   // B-fragments of W_h' = diag(g)*W_h  (64 VGPRs)
  short8 win[2][2];  // B-fragments of W_in (zero-padded K=64)
  float  bc[2];
  #pragma unroll
  for (int n = 0; n < 2; ++n) {
    const int col = c0 + n * 16 + colA;
    const float g = grow[col];
    #pragma unroll
    for (int ks = 0; ks < 8; ++ks) {
      const float* wp = W_h + col * HID + ks * 32 + kq * 8;
      float4v w0 = *(const float4v*)wp;
      float4v w1 = *(const float4v*)(wp + 4);
      short8 f;
      f[0] = f2bf(g * w0[0]); f[1] = f2bf(g * w0[1]);
      f[2] = f2bf(g * w0[2]); f[3] = f2bf(g * w0[3]);
      f[4] = f2bf(g * w1[0]); f[5] = f2bf(g * w1[1]);
      f[6] = f2bf(g * w1[2]); f[7] = f2bf(g * w1[3]);
      wf[n][ks] = f;
    }
    #pragma unroll
    for (int kb = 0; kb < 2; ++kb) {
      short8 f;
      #pragma unroll
      for (int j = 0; j < 8; ++j) {
        int kk = kb * 32 + kq * 8 + j;
        f[j] = (kk < INPUT) ? f2bf(W_in[col * INPUT + kk]) : (short)0;
      }
      win[n][kb] = f;
    }
    bc[n] = b_in[col] + g * b_h[col];
  }

  __syncthreads();   // zero-fill complete before x0 staging

  // ---- stage x_0 into buffer 0 ----
  {
    const float* xt = x + (size_t)brow0 * INPUT;
    for (int e = tid; e < BTILE * INPUT; e += NTH) {
      int r = e / INPUT, c = e - r * INPUT;
      lds[X0 + r * X_STRIDE + c] = f2bf(xt[e]);
    }
  }

  // x-prefetch invariants (threads cover elems tid, tid+512, tid+1024 of 1056)
  const int e0 = tid, e1 = tid + NTH, e2 = tid + 2 * NTH;
  const int r0 = e0 / INPUT, c0x = e0 - r0 * INPUT;
  const int r1 = e1 / INPUT, c1x = e1 - r1 * INPUT;
  const int r2 = e2 / INPUT, c2x = e2 - r2 * INPUT;
  const bool p2 = (e2 < BTILE * INPUT);

  // persistent f32 h master at MFMA C-layout
  float4v hst[2][2];
  #pragma unroll
  for (int m = 0; m < 2; ++m)
    #pragma unroll
    for (int n = 0; n < 2; ++n)
      #pragma unroll
      for (int i = 0; i < 4; ++i) hst[m][n][i] = 0.0f;

  // coalesced store base: wave w owns tile rows 4w..4w+3, lane covers 16B
  float* outg = out + (size_t)(brow0 + 4 * wave) * HID + 4 * lane;
  const int outstep = BATCH * HID;
  const float* xpf = x + (size_t)brow0 * INPUT;
  const int xstep = BATCH * INPUT;

  __syncthreads();   // x0 staged; h0 zeroed

  #pragma unroll 1
  for (int t2 = 0; t2 < T_SEQ / 2; ++t2) {
    CSTEP(H0, X0, H1, X1, 0, 2 * t2);       // even: read buf0, write buf1
    CSTEP(H1, X1, H0, X0, 1, 2 * t2 + 1);   // odd:  read buf1, write buf0
  }

  // h_last == output[T-1]; its f32 rows are still staged in outs[1]
  {
    float* hl = out + (size_t)T_SEQ * BATCH * HID +
                (size_t)(brow0 + 4 * wave) * HID + 4 * lane;
    const float* osr = outs + OUTBUF;   // OW=1 held step T-1
    #pragma unroll
    for (int j = 0; j < 4; ++j)
      *(float4v*)(hl + j * HID) =
          *(const float4v*)(osr + (4 * wave + j) * OUT_STRIDE + 4 * lane);
  }
}

extern "C" void kernel_launch(void* const* d_in, const int* in_sizes, int n_in,
                              void* d_out, int out_size, void* d_ws, size_t ws_size,
                              hipStream_t stream) {
  const float* x    = (const float*)d_in[0];
  const int*   sid  = (const int*)  d_in[1];
  const float* gts  = (const float*)d_in[2];
  const float* W_in = (const float*)d_in[3];
  const float* b_in = (const float*)d_in[4];
  const float* W_h  = (const float*)d_in[5];
  const float* b_h  = (const float*)d_in[6];
  float* out = (float*)d_out;

  ctrnn_kernel<<<BATCH / BTILE, NTH, 0, stream>>>(x, sid, gts, W_in, b_in, W_h, b_h, out);
}